// Round 4
// baseline (285.932 us; speedup 1.0000x reference)
//
#include <hip/hip_runtime.h>
#include <stdint.h>

// Problem constants (match reference)
#define B_TOT 4096
#define T_LEN 2048
#define D_IN  10
#define OUT_N 30
#define TT    32                        // timesteps per LDS tile
#define NT    (T_LEN/TT)                // 64 tiles
#define SMP_BLK 16                      // samples per block
#define ROW_F 12                        // padded row: 10 real + 2 pad floats (48 B)
#define TILE_FLOATS (TT*SMP_BLK*ROW_F)  // 6144 floats = 24 KB per buffer
#define NLD   (TILE_FLOATS/(4*64))      // global_load_lds per wave per tile = 24
#define STEP_B (SMP_BLK*ROW_F*4)        // 768 B per timestep block in LDS

// async global->LDS, width 4 (per-lane arbitrary global addr, linear LDS dest)
#define GLD4(gptr, lptr) __builtin_amdgcn_global_load_lds( \
    (const __attribute__((address_space(1))) void*)(gptr),  \
    (__attribute__((address_space(3))) void*)(lptr), 4, 0, 0)

// DPP cross-lane move (VALU pipe). quad_perm broadcast k: ctrl=k*0x55.
// row_ror:N: ctrl=0x120+N -> dest lane i receives src lane (i-N) mod 16.
template<int CTRL>
__device__ __forceinline__ float dppf(float x) {
    return __int_as_float(
        __builtin_amdgcn_mov_dpp(__float_as_int(x), CTRL, 0xF, 0xF, true));
}

// raw v_exp_f32 (2^x) — avoid libm exp2f's range-fixup instructions
__device__ __forceinline__ float fast_exp2(float x) {
#if __has_builtin(__builtin_amdgcn_exp2f)
    return __builtin_amdgcn_exp2f(x);
#else
    float r; asm("v_exp_f32 %0, %1" : "=v"(r) : "v"(x)); return r;
#endif
}

// Main LSTM scan: 16 lanes per sample.
// lane layout within a 16-lane group (one DPP row): unit u=(lane>>2)&3,
// gate type tau=lane&3. Weight row (PyTorch i,f,g,o order): r = tau*4+u.
// State kept pre-scaled: cs = -2log2(e)*c, so tanh(c)=2*rcp(1+exp2(cs))-1.
__launch_bounds__(256, 1)
__global__ void lstm_scan_kernel(const float* __restrict__ X,
                                 const float* __restrict__ W_ih,
                                 const float* __restrict__ W_hh,
                                 const float* __restrict__ b_ih,
                                 const float* __restrict__ b_hh,
                                 float* __restrict__ hT)
{
    __shared__ float lds[2][TILE_FLOATS];

    const int tid  = threadIdx.x;
    const int lane = tid & 63;
    const int g    = tid >> 4;          // sample within block (0..15)
    const int u    = (tid >> 2) & 3;    // hidden unit
    const int tau  = tid & 3;           // 0=i,1=f,2=g,3=o
    const int r    = tau * 4 + u;       // weight row
    const int w    = tid >> 6;          // wave within block (0..3)

    const float KT = -2.8853900817779268f;   // -2*log2(e)
    const float KS = -1.4426950408889634f;   // -log2(e)
    // pre-activation accumulated PRE-SCALED by mneg; a = fma(k1, rcp(1+exp2(acc)), k0)
    //   tau=0 (i): a = KT*sigmoid   tau=1 (f): a = sigmoid
    //   tau=2 (g): a = tanh         tau=3 (o): a = 2*sigmoid
    const float mneg = (tau == 2) ? KT : KS;
    const float k1   = (tau == 0) ? KT : ((tau == 1) ? 1.0f : 2.0f);
    const float k0   = (tau == 2) ? -1.0f : 0.0f;

    // per-lane constant weights, pre-scaled by mneg (all VGPR-resident)
    float wih[10];
    #pragma unroll
    for (int d0 = 0; d0 < 10; ++d0) wih[d0] = W_ih[r*10 + d0] * mneg;
    // rotated W_hh columns to match row_ror data placement
    const float whhA = W_hh[r*4 +  u        ] * mneg;
    const float whhB = W_hh[r*4 + ((u+3)&3)] * mneg;
    const float whhC = W_hh[r*4 + ((u+2)&3)] * mneg;
    const float whhD = W_hh[r*4 + ((u+1)&3)] * mneg;
    const float bsum = (b_ih[r] + b_hh[r]) * mneg;

    // staging offsets. LDS float index p = (t*SMP_BLK + s)*ROW_F + d.
    // d in [0,10): real data at sample (samp0+s), time (tile*TT+t), dim d.
    // d in {10,11}: pad -> harmless in-bounds dummy (offset 0 + tile shift).
    uint32_t voff[NLD];
    const uint32_t samp0 = (uint32_t)blockIdx.x * SMP_BLK;
    #pragma unroll
    for (int kk = 0; kk < NLD; ++kk) {
        int p   = (w*NLD + kk)*64 + lane;
        int t   = p / (SMP_BLK*ROW_F);
        int rem = p - t*(SMP_BLK*ROW_F);
        int s   = rem / ROW_F;
        int d0  = rem - s*ROW_F;
        voff[kk] = (d0 < 10)
            ? (samp0 + (uint32_t)s) * (uint32_t)(T_LEN*D_IN*4)
              + (uint32_t)(t*40 + d0*4)
            : 0u;                       // pad: reads X[tile*320 + ..], in-bounds
    }
    const char* Xc = (const char*)X;

    // prologue: stage tile 0 into buf 0
    #pragma unroll
    for (int kk = 0; kk < NLD; ++kk)
        GLD4(Xc + voff[kk], &lds[0][(w*NLD+kk)*64]);
    __syncthreads();

    float cs = 0.f, hown = 0.f;

    for (int tile = 0; tile < NT; ++tile) {
        const int cur = tile & 1;
        if (tile + 1 < NT) {
            const uint32_t add = (uint32_t)(tile+1) * (uint32_t)(TT*D_IN*4);
            #pragma unroll
            for (int kk = 0; kk < NLD; ++kk)
                GLD4(Xc + (voff[kk] + add), &lds[cur^1][(w*NLD+kk)*64]);
        }
        // broadcast reads: all 16 lanes of group g read the same 48B row.
        // row t at byte offset g*48 + t*768 (16B-aligned).
        const char* rowp = (const char*)&lds[cur][0] + g*48;

        #define READ_ROW(T_, A_, B_, C_) do {                         \
            A_ = *(const float4*)(rowp + (T_)*STEP_B);                \
            B_ = *(const float4*)(rowp + (T_)*STEP_B + 16);           \
            C_ = *(const float2*)(rowp + (T_)*STEP_B + 32);           \
        } while (0)
        #define XPROJ(A_, B_, C_, DST_) do {                          \
            float acc_ = bsum;                                        \
            acc_ = fmaf(wih[0], A_.x, acc_);                          \
            acc_ = fmaf(wih[1], A_.y, acc_);                          \
            acc_ = fmaf(wih[2], A_.z, acc_);                          \
            acc_ = fmaf(wih[3], A_.w, acc_);                          \
            acc_ = fmaf(wih[4], B_.x, acc_);                          \
            acc_ = fmaf(wih[5], B_.y, acc_);                          \
            acc_ = fmaf(wih[6], B_.z, acc_);                          \
            acc_ = fmaf(wih[7], B_.w, acc_);                          \
            acc_ = fmaf(wih[8], C_.x, acc_);                          \
            acc_ = fmaf(wih[9], C_.y, acc_);                          \
            DST_ = acc_;                                              \
        } while (0)

        // pipeline preload: xacc(0) and x(1) regs
        float4 bA, bB; float2 bC;
        float xaccA;
        {
            float4 a0, b0; float2 c0;
            READ_ROW(0, a0, b0, c0);
            XPROJ(a0, b0, c0, xaccA);
            READ_ROW(1, bA, bB, bC);
        }

        #pragma unroll
        for (int t = 0; t < TT; ++t) {
            // loads for x(t+2) — consumed one full iteration later
            float4 nA, nB; float2 nC;
            if (t + 2 < TT) READ_ROW(t+2, nA, nB, nC);
            // x-projection for step t+1 (independent: fills chain stalls)
            float xaccB = 0.f;
            if (t + 1 < TT) XPROJ(bA, bB, bC, xaccB);
            // ---- serial chain for step t ----
            float hB = dppf<0x124>(hown);   // h[(u-1)&3]
            float hC = dppf<0x128>(hown);   // h[(u-2)&3]
            float hD = dppf<0x12C>(hown);   // h[(u+1)&3]
            float u1 = fmaf(whhA, hown, xaccA);     // starts before DPPs land
            float p1 = fmaf(whhB, hB, u1);
            float p2 = fmaf(whhD, hD, whhC * hC);
            float acc = p1 + p2;
            float e  = fast_exp2(acc);
            float a  = fmaf(k1, __builtin_amdgcn_rcpf(1.0f + e), k0);
            float gi = dppf<0x00>(a);       // KT*sigmoid(i)
            float gf = dppf<0x55>(a);       // sigmoid(f)
            float gg = dppf<0xAA>(a);       // tanh(g)
            float go = dppf<0xFF>(a);       // 2*sigmoid(o)
            float mgo = -0.5f * go;         // off-chain
            cs = fmaf(gf, cs, gi * gg);     // cs = KT * c
            float e2 = fast_exp2(cs);
            float r2 = __builtin_amdgcn_rcpf(1.0f + e2);
            hown = fmaf(go, r2, mgo);       // = sigmoid(o)*tanh(c)
            // rotate pipeline (register renaming after unroll)
            bA = nA; bB = nB; bC = nC;
            xaccA = xaccB;
        }
        #undef READ_ROW
        #undef XPROJ
        __syncthreads();  // drains next-tile prefetch + protects buffer swap
    }

    if (tau == 0) hT[(samp0 + g)*4 + u] = hown;
}

// Head: logits = hT @ W_out^T + b_out, then softmax. One thread per sample.
__global__ void head_kernel(const float* __restrict__ hT,
                            const float* __restrict__ W_out,
                            const float* __restrict__ b_out,
                            float* __restrict__ out)
{
    int b = blockIdx.x * blockDim.x + threadIdx.x;
    if (b >= B_TOT) return;
    float4 h = ((const float4*)hT)[b];
    float lg[OUT_N];
    float m = -1e30f;
    #pragma unroll
    for (int o = 0; o < OUT_N; ++o) {
        float v = b_out[o];
        v = fmaf(W_out[o*4+0], h.x, v);
        v = fmaf(W_out[o*4+1], h.y, v);
        v = fmaf(W_out[o*4+2], h.z, v);
        v = fmaf(W_out[o*4+3], h.w, v);
        lg[o] = v;
        m = fmaxf(m, v);
    }
    float s = 0.f;
    #pragma unroll
    for (int o = 0; o < OUT_N; ++o) {
        float e = fast_exp2((lg[o] - m) * 1.4426950408889634f);
        lg[o] = e;
        s += e;
    }
    float rs = 1.0f / s;
    #pragma unroll
    for (int o = 0; o < OUT_N; ++o) out[(size_t)b*OUT_N + o] = lg[o] * rs;
}

extern "C" void kernel_launch(void* const* d_in, const int* in_sizes, int n_in,
                              void* d_out, int out_size, void* d_ws, size_t ws_size,
                              hipStream_t stream)
{
    const float* X     = (const float*)d_in[0];
    const float* W_ih  = (const float*)d_in[1];
    const float* W_hh  = (const float*)d_in[2];
    const float* b_ih  = (const float*)d_in[3];
    const float* b_hh  = (const float*)d_in[4];
    const float* W_out = (const float*)d_in[5];
    const float* b_out = (const float*)d_in[6];
    float* out = (float*)d_out;
    float* hTs = (float*)d_ws;   // 4096*4 floats = 64 KB scratch

    lstm_scan_kernel<<<B_TOT/SMP_BLK, 256, 0, stream>>>(X, W_ih, W_hh, b_ih, b_hh, hTs);
    head_kernel<<<B_TOT/256, 256, 0, stream>>>(hTs, W_out, b_out, out);
}